// Round 6
// baseline (162.332 us; speedup 1.0000x reference)
//
#include <hip/hip_runtime.h>
#include <hip/hip_bf16.h>

#define NHEAD 4
#define DIN 128
#define DOUT 128

typedef __attribute__((ext_vector_type(8))) short bf16x8;
typedef __attribute__((ext_vector_type(4))) float f32x4;

__device__ __forceinline__ short bfb(float f) {
    __hip_bfloat16 h = __float2bfloat16(f);
    return *reinterpret_cast<short*>(&h);
}
__device__ __forceinline__ float bf2f(unsigned short u) {
    return __uint_as_float(((unsigned int)u) << 16);
}
__device__ __forceinline__ unsigned int pk2(float lo, float hi) {
    return (unsigned int)(unsigned short)bfb(lo) |
           ((unsigned int)(unsigned short)bfb(hi) << 16);
}

// ---------------- K0: convert feat and W0|W1 to bf16 ----------------
__global__ __launch_bounds__(256) void k0_cvt(
    const float* __restrict__ feat, const float* __restrict__ W0,
    const float* __restrict__ W1, uint4* __restrict__ featbf,
    uint4* __restrict__ Wbf, int nfeat8)
{
    const int i = blockIdx.x * blockDim.x + threadIdx.x;
    const int nW8 = (2 * DOUT * DIN) / 8;     // 4096 groups of 8
    if (i < nfeat8) {
        float4 a = ((const float4*)feat)[2 * i];
        float4 b = ((const float4*)feat)[2 * i + 1];
        featbf[i] = make_uint4(pk2(a.x, a.y), pk2(a.z, a.w),
                               pk2(b.x, b.y), pk2(b.z, b.w));
    } else if (i < nfeat8 + nW8) {
        int j = i - nfeat8;
        const float* s = (j < nW8 / 2) ? (W0 + (size_t)j * 8)
                                       : (W1 + (size_t)(j - nW8 / 2) * 8);
        float4 a = ((const float4*)s)[0];
        float4 b = ((const float4*)s)[1];
        Wbf[j] = make_uint4(pk2(a.x, a.y), pk2(a.z, a.w),
                            pk2(b.x, b.y), pk2(b.z, b.w));
    }
}

// ---------------- K1: MFMA dual projection + ReLU + logits + h_self layernorm -------
// 512 threads = 8 waves; wave w owns 32 channels (one head): w<4 -> self half
// (emits 0.5*layernorm(h_self) as bf16 + att_self), w>=4 -> h_neigh + att_neigh.
// A = weights (bf16, regs), B = feat tile (bf16), next-tile B prefetched.
#define NPB 64   // nodes per block (4 tiles)

__global__ __launch_bounds__(512) void k1_mfma(
    const uint4* __restrict__ featbf,      // [n][16] (128 bf16 per row)
    const uint4* __restrict__ Wbf,         // [256][16]
    const float* __restrict__ b0, const float* __restrict__ b1,
    const float* __restrict__ att, const float* __restrict__ scale,
    const float* __restrict__ offset,
    unsigned short* __restrict__ nsbuf, unsigned short* __restrict__ h_neigh,
    float* __restrict__ att_self, float* __restrict__ att_neigh, int n)
{
    const int t = threadIdx.x;
    const int w = t >> 6;            // wave 0..7
    const int lane = t & 63;
    const int col = lane & 15;       // node-within-tile (B col / D col); W row sel
    const int rg = lane >> 4;        // k group; D row group
    const bool selfhalf = (w < 4);
    const int hd = w & 3;

    // A fragments: W rows w*32 + ct*16 + col
    bf16x8 afr[2][4];
    #pragma unroll
    for (int ct = 0; ct < 2; ct++) {
        const uint4* wr = Wbf + (size_t)(w * 32 + ct * 16 + col) * 16;
        #pragma unroll
        for (int kk = 0; kk < 4; kk++) {
            uint4 u = wr[kk * 4 + rg];
            *(uint4*)&afr[ct][kk] = u;
        }
    }
    // epilogue params for channels chg = w*32 + ct*16 + rg*4 + j
    float4 bias4[2], att4[2], sc4[2], of4[2];
    #pragma unroll
    for (int ct = 0; ct < 2; ct++) {
        int chg = w * 32 + ct * 16 + rg * 4;      // 0..255
        int chm = chg & 127;
        bias4[ct] = *(const float4*)((selfhalf ? b0 : b1) + chm);
        att4[ct]  = *(const float4*)(att + chg);
        sc4[ct]   = *(const float4*)(scale + 128 + chm);   // b=1 params
        of4[ct]   = *(const float4*)(offset + 128 + chm);
    }

    const int ntiles = (n + 15) >> 4;
    const int tile0 = blockIdx.x * (NPB / 16);
    const int tile1 = min(tile0 + NPB / 16, ntiles);
    if (tile0 >= ntiles) return;

    bf16x8 cur[4], nxt[4];
    {
        int node = tile0 * 16 + col;
        if (node < n) {
            const uint4* fr = featbf + (size_t)node * 16;
            #pragma unroll
            for (int kk = 0; kk < 4; kk++) { uint4 u = fr[kk * 4 + rg]; *(uint4*)&cur[kk] = u; }
        } else {
            #pragma unroll
            for (int kk = 0; kk < 4; kk++) { uint4 z = make_uint4(0,0,0,0); *(uint4*)&cur[kk] = z; }
        }
    }

    for (int tile = tile0; tile < tile1; tile++) {
        // prefetch next tile's B fragments (consumed next iteration)
        if (tile + 1 < tile1) {
            int node = (tile + 1) * 16 + col;
            if (node < n) {
                const uint4* fr = featbf + (size_t)node * 16;
                #pragma unroll
                for (int kk = 0; kk < 4; kk++) { uint4 u = fr[kk * 4 + rg]; *(uint4*)&nxt[kk] = u; }
            } else {
                #pragma unroll
                for (int kk = 0; kk < 4; kk++) { uint4 z = make_uint4(0,0,0,0); *(uint4*)&nxt[kk] = z; }
            }
        }

        f32x4 acc[2] = {{0.f,0.f,0.f,0.f},{0.f,0.f,0.f,0.f}};
        #pragma unroll
        for (int kk = 0; kk < 4; kk++) {
            acc[0] = __builtin_amdgcn_mfma_f32_16x16x32_bf16(afr[0][kk], cur[kk], acc[0], 0, 0, 0);
            acc[1] = __builtin_amdgcn_mfma_f32_16x16x32_bf16(afr[1][kk], cur[kk], acc[1], 0, 0, 0);
        }

        const int node = tile * 16 + col;
        const bool valid = node < n;

        float v[2][4];
        float p = 0.f;
        #pragma unroll
        for (int ct = 0; ct < 2; ct++) {
            v[ct][0] = fmaxf(acc[ct][0] + bias4[ct].x, 0.f);
            v[ct][1] = fmaxf(acc[ct][1] + bias4[ct].y, 0.f);
            v[ct][2] = fmaxf(acc[ct][2] + bias4[ct].z, 0.f);
            v[ct][3] = fmaxf(acc[ct][3] + bias4[ct].w, 0.f);
            p += v[ct][0] * att4[ct].x + v[ct][1] * att4[ct].y
               + v[ct][2] * att4[ct].z + v[ct][3] * att4[ct].w;
        }
        p += __shfl_xor(p, 16);
        p += __shfl_xor(p, 32);

        if (selfhalf) {
            // layernorm over the head's 32 channels (4 rg groups x 2ct x 4j)
            float s = v[0][0]+v[0][1]+v[0][2]+v[0][3]+v[1][0]+v[1][1]+v[1][2]+v[1][3];
            s += __shfl_xor(s, 16);
            s += __shfl_xor(s, 32);
            float m = s * (1.f / 32.f);
            float q = 0.f;
            #pragma unroll
            for (int ct = 0; ct < 2; ct++)
                #pragma unroll
                for (int j = 0; j < 4; j++) { float d = v[ct][j] - m; q += d * d; }
            q += __shfl_xor(q, 16);
            q += __shfl_xor(q, 32);
            float r = rsqrtf(q * (1.f / 32.f) + 1e-9f);
            #pragma unroll
            for (int ct = 0; ct < 2; ct++) {
                float n0 = 0.5f * ((v[ct][0] - m) * sc4[ct].x * r + of4[ct].x);
                float n1 = 0.5f * ((v[ct][1] - m) * sc4[ct].y * r + of4[ct].y);
                float n2 = 0.5f * ((v[ct][2] - m) * sc4[ct].z * r + of4[ct].z);
                float n3 = 0.5f * ((v[ct][3] - m) * sc4[ct].w * r + of4[ct].w);
                ushort4 st;
                st.x = (unsigned short)bfb(n0); st.y = (unsigned short)bfb(n1);
                st.z = (unsigned short)bfb(n2); st.w = (unsigned short)bfb(n3);
                if (valid)
                    *(ushort4*)(nsbuf + (size_t)node * DOUT + hd * 32 + ct * 16 + rg * 4) = st;
            }
            if (rg == 0 && valid)
                att_self[(size_t)node * NHEAD + hd] = p > 0.f ? p : 0.2f * p;
        } else {
            #pragma unroll
            for (int ct = 0; ct < 2; ct++) {
                ushort4 st;
                st.x = (unsigned short)bfb(v[ct][0]); st.y = (unsigned short)bfb(v[ct][1]);
                st.z = (unsigned short)bfb(v[ct][2]); st.w = (unsigned short)bfb(v[ct][3]);
                if (valid)
                    *(ushort4*)(h_neigh + (size_t)node * DOUT + hd * 32 + ct * 16 + rg * 4) = st;
            }
            if (rg == 0 && valid)
                att_neigh[(size_t)node * NHEAD + hd] = p > 0.f ? p : 0.2f * p;
        }

        #pragma unroll
        for (int kk = 0; kk < 4; kk++) cur[kk] = nxt[kk];
    }
}

// ---------------- K2: CSR offsets by binary search on sorted edge_row ----------------
__global__ void k2_rowptr(const int* __restrict__ erow, int* __restrict__ rowptr,
                          int n_nodes, int nedge)
{
    int n = blockIdx.x * blockDim.x + threadIdx.x;
    if (n > n_nodes) return;
    int lo = 0, hi = nedge;
    while (lo < hi) { int mid = (lo + hi) >> 1; if (erow[mid] < n) lo = mid + 1; else hi = mid; }
    rowptr[n] = lo;
}

// ---------------- K2b: per-edge softmax numerators (stream) ----------------
__global__ __launch_bounds__(256) void k_edgew(
    const int* __restrict__ erow, const int* __restrict__ ecol,
    const float* __restrict__ eval,
    const float* __restrict__ att_self, const float* __restrict__ att_neigh,
    float* __restrict__ wbuf, int E)
{
    int e = blockIdx.x * blockDim.x + threadIdx.x;
    if (e >= E) return;
    int r = erow[e], c = ecol[e];
    float4 s  = *(const float4*)(att_self  + (size_t)r * NHEAD);
    float4 nb = *(const float4*)(att_neigh + (size_t)c * NHEAD);
    float ev = eval[e];
    float4 wv;
    wv.x = __expf(s.x + nb.x) * ev;
    wv.y = __expf(s.y + nb.y) * ev;
    wv.z = __expf(s.z + nb.z) * ev;
    wv.w = __expf(s.w + nb.w) * ev;
    *(float4*)(wbuf + (size_t)e * NHEAD) = wv;
}

// ---------------- K3: weighted aggregate + agg layernorm + combine ----------------
// 256 threads = 8 nodes/block, 32 lanes/node, 4 channels/thread.
// 3-deep gather pipeline: hv in flight for 2 batches while consuming one;
// cols prefetched 3 batches ahead. wh is a precomputed stream (no exp here).
__device__ __forceinline__ float group8_sum(float v) {
    v += __shfl_xor(v, 1);
    v += __shfl_xor(v, 2);
    v += __shfl_xor(v, 4);
    return v;
}

__global__ __launch_bounds__(256) void k3_agg(
    const int* __restrict__ rowptr, const int* __restrict__ ecol,
    const float* __restrict__ wbuf,
    const unsigned short* __restrict__ nsbuf, const unsigned short* __restrict__ h_neigh,
    const float* __restrict__ scale, const float* __restrict__ offset,
    float* __restrict__ out, int n_nodes)
{
    const int t = threadIdx.x;
    const int g = t >> 5;
    const int lane = t & 31;
    const int nid = blockIdx.x * 8 + g;
    if (nid >= n_nodes) return;
    const int head = lane >> 3;
    const int c4 = lane * 4;

    const int start = rowptr[nid], end = rowptr[nid + 1];

    float acc0 = 0.f, acc1 = 0.f, acc2 = 0.f, acc3 = 0.f, sumw = 0.f;

    int cB[4], cC[4];
    float wA[4], wB[4];
    ushort4 hA[4], hB[4];
    {
        int cA[4];
        #pragma unroll
        for (int i = 0; i < 4; i++) cA[i] = (start + i     < end) ? ecol[start + i]     : 0;
        #pragma unroll
        for (int i = 0; i < 4; i++) cB[i] = (start + 4 + i < end) ? ecol[start + 4 + i] : 0;
        #pragma unroll
        for (int i = 0; i < 4; i++) cC[i] = (start + 8 + i < end) ? ecol[start + 8 + i] : 0;
        #pragma unroll
        for (int i = 0; i < 4; i++) {
            wA[i] = (start + i < end) ? wbuf[(size_t)(start + i) * NHEAD + head] : 0.f;
            hA[i] = *(const ushort4*)(h_neigh + (size_t)cA[i] * DOUT + c4);
        }
        #pragma unroll
        for (int i = 0; i < 4; i++) {
            wB[i] = (start + 4 + i < end) ? wbuf[(size_t)(start + 4 + i) * NHEAD + head] : 0.f;
            hB[i] = *(const ushort4*)(h_neigh + (size_t)cB[i] * DOUT + c4);
        }
    }

    for (int e = start; e < end; e += 4) {
        // issue stage C gathers (cols known 2 iterations ago)
        float wC[4]; ushort4 hC[4];
        #pragma unroll
        for (int i = 0; i < 4; i++) {
            wC[i] = (e + 8 + i < end) ? wbuf[(size_t)(e + 8 + i) * NHEAD + head] : 0.f;
            hC[i] = *(const ushort4*)(h_neigh + (size_t)cC[i] * DOUT + c4);
        }
        int cD[4];
        #pragma unroll
        for (int i = 0; i < 4; i++)
            cD[i] = (e + 12 + i < end) ? ecol[e + 12 + i] : 0;

        // consume stage A
        #pragma unroll
        for (int i = 0; i < 4; i++) {
            float wh = wA[i];
            sumw += wh;
            acc0 = fmaf(wh, bf2f(hA[i].x), acc0);
            acc1 = fmaf(wh, bf2f(hA[i].y), acc1);
            acc2 = fmaf(wh, bf2f(hA[i].z), acc2);
            acc3 = fmaf(wh, bf2f(hA[i].w), acc3);
        }
        // rotate pipeline
        #pragma unroll
        for (int i = 0; i < 4; i++) {
            wA[i] = wB[i]; hA[i] = hB[i];
            wB[i] = wC[i]; hB[i] = hC[i];
            cC[i] = cD[i];
        }
    }

    const float rden = 1.f / fmaxf(sumw, 1e-10f);
    float a0 = acc0 * rden, a1 = acc1 * rden, a2 = acc2 * rden, a3 = acc3 * rden;

    // layernorm of agg over the head's 32 channels (8 lanes x 4)
    float m0 = group8_sum(a0 + a1 + a2 + a3) * (1.f / 32.f);
    float d0 = a0 - m0, d1 = a1 - m0, d2 = a2 - m0, d3 = a3 - m0;
    float v0 = group8_sum(d0*d0 + d1*d1 + d2*d2 + d3*d3) * (1.f / 32.f);
    float r0 = rsqrtf(v0 + 1e-9f);
    float4 sc0 = *(const float4*)(scale + c4);
    float4 of0 = *(const float4*)(offset + c4);

    ushort4 nsv = *(const ushort4*)(nsbuf + (size_t)nid * DOUT + c4);

    float4 o;
    o.x = 0.5f * (d0 * sc0.x * r0 + of0.x) + bf2f(nsv.x);
    o.y = 0.5f * (d1 * sc0.y * r0 + of0.y) + bf2f(nsv.y);
    o.z = 0.5f * (d2 * sc0.z * r0 + of0.z) + bf2f(nsv.z);
    o.w = 0.5f * (d3 * sc0.w * r0 + of0.w) + bf2f(nsv.w);
    *(float4*)(out + (size_t)nid * DOUT + c4) = o;
}

extern "C" void kernel_launch(void* const* d_in, const int* in_sizes, int n_in,
                              void* d_out, int out_size, void* d_ws, size_t ws_size,
                              hipStream_t stream) {
    const float* feat  = (const float*)d_in[0];
    const int*   erow  = (const int*)  d_in[1];
    const int*   ecol  = (const int*)  d_in[2];
    const float* eval  = (const float*)d_in[3];
    const float* W0    = (const float*)d_in[4];
    const float* b0    = (const float*)d_in[5];
    const float* W1    = (const float*)d_in[6];
    const float* b1    = (const float*)d_in[7];
    const float* att   = (const float*)d_in[8];
    const float* scale = (const float*)d_in[9];
    const float* offs  = (const float*)d_in[10];
    const int n = in_sizes[0] / DIN;
    const int E = in_sizes[2];

    unsigned short* featbf  = (unsigned short*)d_ws;                 // n*128
    unsigned short* Wbf     = featbf + (size_t)n * DOUT;             // 256*128
    unsigned short* nsbuf   = Wbf + 2 * DOUT * DIN;                  // n*128
    unsigned short* h_neigh = nsbuf + (size_t)n * DOUT;              // n*128
    float* att_self  = (float*)(h_neigh + (size_t)n * DOUT);
    float* att_neigh = att_self  + (size_t)n * NHEAD;
    float* wbuf      = att_neigh + (size_t)n * NHEAD;                // E*4
    int*   rowptr    = (int*)(wbuf + (size_t)E * NHEAD);

    const int nfeat8 = n * (DIN / 8);
    k0_cvt<<<(nfeat8 + 4096 + 255) / 256, 256, 0, stream>>>(
        feat, W0, W1, (uint4*)featbf, (uint4*)Wbf, nfeat8);
    k1_mfma<<<(n + NPB - 1) / NPB, 512, 0, stream>>>(
        (const uint4*)featbf, (const uint4*)Wbf, b0, b1, att, scale, offs,
        nsbuf, h_neigh, att_self, att_neigh, n);
    k2_rowptr<<<(n + 1 + 255) / 256, 256, 0, stream>>>(erow, rowptr, n, E);
    k_edgew<<<(E + 255) / 256, 256, 0, stream>>>(erow, ecol, eval,
                                                 att_self, att_neigh, wbuf, E);
    k3_agg<<<(n + 7) / 8, 256, 0, stream>>>(rowptr, ecol, wbuf, nsbuf, h_neigh,
                                            scale, offs, (float*)d_out, n);
}

// Round 7
// 138.062 us; speedup vs baseline: 1.1758x; 1.1758x over previous
//
#include <hip/hip_runtime.h>
#include <hip/hip_bf16.h>

#define NHEAD 4
#define DIN 128
#define DOUT 128

typedef __attribute__((ext_vector_type(8))) short bf16x8;
typedef __attribute__((ext_vector_type(4))) float f32x4;

__device__ __forceinline__ short bfb(float f) {
    __hip_bfloat16 h = __float2bfloat16(f);
    return *reinterpret_cast<short*>(&h);
}
__device__ __forceinline__ float bf2f(unsigned short u) {
    return __uint_as_float(((unsigned int)u) << 16);
}
__device__ __forceinline__ float2 bfpair(unsigned int u) {
    float2 r;
    r.x = __uint_as_float(u << 16);
    r.y = __uint_as_float(u & 0xFFFF0000u);
    return r;
}
__device__ __forceinline__ unsigned int pk2(float lo, float hi) {
    return (unsigned int)(unsigned short)bfb(lo) |
           ((unsigned int)(unsigned short)bfb(hi) << 16);
}

// ---------------- K0: convert feat and W0|W1 to bf16 ----------------
__global__ __launch_bounds__(256) void k0_cvt(
    const float* __restrict__ feat, const float* __restrict__ W0,
    const float* __restrict__ W1, uint4* __restrict__ featbf,
    uint4* __restrict__ Wbf, int nfeat8)
{
    const int i = blockIdx.x * blockDim.x + threadIdx.x;
    const int nW8 = (2 * DOUT * DIN) / 8;     // 4096 groups of 8
    if (i < nfeat8) {
        float4 a = ((const float4*)feat)[2 * i];
        float4 b = ((const float4*)feat)[2 * i + 1];
        featbf[i] = make_uint4(pk2(a.x, a.y), pk2(a.z, a.w),
                               pk2(b.x, b.y), pk2(b.z, b.w));
    } else if (i < nfeat8 + nW8) {
        int j = i - nfeat8;
        const float* s = (j < nW8 / 2) ? (W0 + (size_t)j * 8)
                                       : (W1 + (size_t)(j - nW8 / 2) * 8);
        float4 a = ((const float4*)s)[0];
        float4 b = ((const float4*)s)[1];
        Wbf[j] = make_uint4(pk2(a.x, a.y), pk2(a.z, a.w),
                            pk2(b.x, b.y), pk2(b.z, b.w));
    }
}

// ---------------- K1: MFMA dual projection + ReLU + logits + h_self layernorm -------
// 512 threads = 8 waves; wave w owns 32 channels (one head): w<4 -> self half
// (emits 0.5*layernorm(h_self) bf16 + att_self), w>=4 -> h_neigh + att_neigh.
// Feat tile (64 nodes, bf16) staged ONCE per block in LDS (XOR-swizzled 16B slots);
// all waves read B-fragments from LDS -> no redundant global loads.
#define NPB 64   // nodes per block (4 tiles)

__global__ __launch_bounds__(512) void k1_mfma(
    const uint4* __restrict__ featbf,      // [n][16] (128 bf16 per row)
    const uint4* __restrict__ Wbf,         // [256][16]
    const float* __restrict__ b0, const float* __restrict__ b1,
    const float* __restrict__ att, const float* __restrict__ scale,
    const float* __restrict__ offset,
    unsigned short* __restrict__ nsbuf, unsigned short* __restrict__ h_neigh,
    float* __restrict__ att_self, float* __restrict__ att_neigh, int n)
{
    __shared__ uint4 lds[NPB * 16];        // 16 KB: 64 nodes x 16 slots of 16B
    const int t = threadIdx.x;
    const int w = t >> 6;            // wave 0..7
    const int lane = t & 63;
    const int col = lane & 15;       // node-within-tile (B col / D col); W row sel
    const int rg = lane >> 4;        // k group; D row group
    const bool selfhalf = (w < 4);
    const int hd = w & 3;

    // A fragments: W rows w*32 + ct*16 + col
    bf16x8 afr[2][4];
    #pragma unroll
    for (int ct = 0; ct < 2; ct++) {
        const uint4* wr = Wbf + (size_t)(w * 32 + ct * 16 + col) * 16;
        #pragma unroll
        for (int kk = 0; kk < 4; kk++) {
            uint4 u = wr[kk * 4 + rg];
            *(uint4*)&afr[ct][kk] = u;
        }
    }
    // epilogue params for channels chg = w*32 + ct*16 + rg*4 + j
    float4 bias4[2], att4[2], sc4[2], of4[2];
    #pragma unroll
    for (int ct = 0; ct < 2; ct++) {
        int chg = w * 32 + ct * 16 + rg * 4;      // 0..255
        int chm = chg & 127;
        bias4[ct] = *(const float4*)((selfhalf ? b0 : b1) + chm);
        att4[ct]  = *(const float4*)(att + chg);
        sc4[ct]   = *(const float4*)(scale + 128 + chm);   // b=1 params
        of4[ct]   = *(const float4*)(offset + 128 + chm);
    }

    const int base_node = blockIdx.x * NPB;
    // stage 64 node rows: thread t handles LDS slots t and t+512 (uint4 units).
    // swizzle: LDS linear; SOURCE slot = slot ^ (node_local & 7)  (involution)
    #pragma unroll
    for (int j = 0; j < 2; j++) {
        int li = j * 512 + t;                 // lds uint4 index
        int nl = li >> 4;                     // node local 0..63
        int sl = li & 15;                     // 16B slot
        int ng = base_node + nl;
        if (ng >= n) ng = n - 1;
        lds[li] = featbf[(size_t)ng * 16 + (sl ^ (nl & 7))];
    }
    __syncthreads();

    const int ntiles = (n + 15) >> 4;
    const int tile0 = blockIdx.x * (NPB / 16);
    const int tile1 = min(tile0 + NPB / 16, ntiles);

    for (int tile = tile0; tile < tile1; tile++) {
        const int tt = tile - tile0;
        const int nl = tt * 16 + col;
        // B-fragments from LDS (swizzled read)
        bf16x8 bfr[4];
        #pragma unroll
        for (int kk = 0; kk < 4; kk++) {
            uint4 u = lds[nl * 16 + ((kk * 4 + rg) ^ (col & 7))];
            *(uint4*)&bfr[kk] = u;
        }

        f32x4 acc[2] = {{0.f,0.f,0.f,0.f},{0.f,0.f,0.f,0.f}};
        #pragma unroll
        for (int kk = 0; kk < 4; kk++) {
            acc[0] = __builtin_amdgcn_mfma_f32_16x16x32_bf16(afr[0][kk], bfr[kk], acc[0], 0, 0, 0);
            acc[1] = __builtin_amdgcn_mfma_f32_16x16x32_bf16(afr[1][kk], bfr[kk], acc[1], 0, 0, 0);
        }

        const int node = tile * 16 + col;
        const bool valid = node < n;

        float v[2][4];
        float p = 0.f;
        #pragma unroll
        for (int ct = 0; ct < 2; ct++) {
            v[ct][0] = fmaxf(acc[ct][0] + bias4[ct].x, 0.f);
            v[ct][1] = fmaxf(acc[ct][1] + bias4[ct].y, 0.f);
            v[ct][2] = fmaxf(acc[ct][2] + bias4[ct].z, 0.f);
            v[ct][3] = fmaxf(acc[ct][3] + bias4[ct].w, 0.f);
            p += v[ct][0] * att4[ct].x + v[ct][1] * att4[ct].y
               + v[ct][2] * att4[ct].z + v[ct][3] * att4[ct].w;
        }
        p += __shfl_xor(p, 16);
        p += __shfl_xor(p, 32);

        if (selfhalf) {
            float s = v[0][0]+v[0][1]+v[0][2]+v[0][3]+v[1][0]+v[1][1]+v[1][2]+v[1][3];
            s += __shfl_xor(s, 16);
            s += __shfl_xor(s, 32);
            float m = s * (1.f / 32.f);
            float q = 0.f;
            #pragma unroll
            for (int ct = 0; ct < 2; ct++)
                #pragma unroll
                for (int j = 0; j < 4; j++) { float d = v[ct][j] - m; q += d * d; }
            q += __shfl_xor(q, 16);
            q += __shfl_xor(q, 32);
            float r = rsqrtf(q * (1.f / 32.f) + 1e-9f);
            #pragma unroll
            for (int ct = 0; ct < 2; ct++) {
                float n0 = 0.5f * ((v[ct][0] - m) * sc4[ct].x * r + of4[ct].x);
                float n1 = 0.5f * ((v[ct][1] - m) * sc4[ct].y * r + of4[ct].y);
                float n2 = 0.5f * ((v[ct][2] - m) * sc4[ct].z * r + of4[ct].z);
                float n3 = 0.5f * ((v[ct][3] - m) * sc4[ct].w * r + of4[ct].w);
                ushort4 st;
                st.x = (unsigned short)bfb(n0); st.y = (unsigned short)bfb(n1);
                st.z = (unsigned short)bfb(n2); st.w = (unsigned short)bfb(n3);
                if (valid)
                    *(ushort4*)(nsbuf + (size_t)node * DOUT + hd * 32 + ct * 16 + rg * 4) = st;
            }
            if (rg == 0 && valid)
                att_self[(size_t)node * NHEAD + hd] = p > 0.f ? p : 0.2f * p;
        } else {
            #pragma unroll
            for (int ct = 0; ct < 2; ct++) {
                ushort4 st;
                st.x = (unsigned short)bfb(v[ct][0]); st.y = (unsigned short)bfb(v[ct][1]);
                st.z = (unsigned short)bfb(v[ct][2]); st.w = (unsigned short)bfb(v[ct][3]);
                if (valid)
                    *(ushort4*)(h_neigh + (size_t)node * DOUT + hd * 32 + ct * 16 + rg * 4) = st;
            }
            if (rg == 0 && valid)
                att_neigh[(size_t)node * NHEAD + hd] = p > 0.f ? p : 0.2f * p;
        }
    }
}

// ---------------- K2: CSR offsets by binary search on sorted edge_row ----------------
__global__ void k2_rowptr(const int* __restrict__ erow, int* __restrict__ rowptr,
                          int n_nodes, int nedge)
{
    int n = blockIdx.x * blockDim.x + threadIdx.x;
    if (n > n_nodes) return;
    int lo = 0, hi = nedge;
    while (lo < hi) { int mid = (lo + hi) >> 1; if (erow[mid] < n) lo = mid + 1; else hi = mid; }
    rowptr[n] = lo;
}

// ---------------- K3: fused softmax + weighted aggregate + agg layernorm + combine --
// 256 threads = 16 nodes/block, 16 lanes/node, 8 channels/thread.
// 3-deep pinned pipeline: stages A(consume)/B(in flight)/C(issued this iter);
// sched_barrier(0) prevents the compiler from sinking the C-issues to their uses.
__device__ __forceinline__ float group4_sum(float v) {
    v += __shfl_xor(v, 1);
    v += __shfl_xor(v, 2);
    return v;
}

__global__ __launch_bounds__(256) void k3_agg(
    const int* __restrict__ rowptr, const int* __restrict__ ecol,
    const float* __restrict__ eval,
    const float* __restrict__ att_self, const float* __restrict__ att_neigh,
    const unsigned short* __restrict__ nsbuf, const unsigned short* __restrict__ h_neigh,
    const float* __restrict__ scale, const float* __restrict__ offset,
    float* __restrict__ out, int n_nodes)
{
    const int t = threadIdx.x;
    const int g = t >> 4;
    const int lane = t & 15;
    const int nid = blockIdx.x * 16 + g;
    if (nid >= n_nodes) return;
    const int head = lane >> 2;
    const int c8 = lane * 8;

    const int start = rowptr[nid], end = rowptr[nid + 1];
    const float as = att_self[(size_t)nid * NHEAD + head];

    float acc[8];
    #pragma unroll
    for (int j = 0; j < 8; j++) acc[j] = 0.f;
    float sumw = 0.f;

    // prologue: load stages A and B; cols for stage C
    float evA[4], anA[4], evB[4], anB[4];
    uint4 hvA[4], hvB[4];
    int cC[4];
    {
        int cA[4], cB[4];
        #pragma unroll
        for (int i = 0; i < 4; i++) cA[i] = (start + i     < end) ? ecol[start + i]     : 0;
        #pragma unroll
        for (int i = 0; i < 4; i++) cB[i] = (start + 4 + i < end) ? ecol[start + 4 + i] : 0;
        #pragma unroll
        for (int i = 0; i < 4; i++) cC[i] = (start + 8 + i < end) ? ecol[start + 8 + i] : 0;
        #pragma unroll
        for (int i = 0; i < 4; i++) {
            evA[i] = (start + i < end) ? eval[start + i] : 0.f;
            anA[i] = att_neigh[(size_t)cA[i] * NHEAD + head];
            hvA[i] = *(const uint4*)(h_neigh + (size_t)cA[i] * DOUT + c8);
        }
        #pragma unroll
        for (int i = 0; i < 4; i++) {
            evB[i] = (start + 4 + i < end) ? eval[start + 4 + i] : 0.f;
            anB[i] = att_neigh[(size_t)cB[i] * NHEAD + head];
            hvB[i] = *(const uint4*)(h_neigh + (size_t)cB[i] * DOUT + c8);
        }
    }

    for (int e = start; e < end; e += 4) {
        // issue stage C loads (edges e+8..e+11)
        float evC[4], anC[4];
        uint4 hvC[4];
        #pragma unroll
        for (int i = 0; i < 4; i++) {
            evC[i] = (e + 8 + i < end) ? eval[e + 8 + i] : 0.f;
            anC[i] = att_neigh[(size_t)cC[i] * NHEAD + head];
            hvC[i] = *(const uint4*)(h_neigh + (size_t)cC[i] * DOUT + c8);
        }
        int cD[4];
        #pragma unroll
        for (int i = 0; i < 4; i++)
            cD[i] = (e + 12 + i < end) ? ecol[e + 12 + i] : 0;

        __builtin_amdgcn_sched_barrier(0);   // keep C-issues above A-consumption

        // consume stage A
        #pragma unroll
        for (int i = 0; i < 4; i++) {
            float wh = __expf(as + anA[i]) * evA[i];
            sumw += wh;
            float2 p;
            p = bfpair(hvA[i].x); acc[0] = fmaf(wh, p.x, acc[0]); acc[1] = fmaf(wh, p.y, acc[1]);
            p = bfpair(hvA[i].y); acc[2] = fmaf(wh, p.x, acc[2]); acc[3] = fmaf(wh, p.y, acc[3]);
            p = bfpair(hvA[i].z); acc[4] = fmaf(wh, p.x, acc[4]); acc[5] = fmaf(wh, p.y, acc[5]);
            p = bfpair(hvA[i].w); acc[6] = fmaf(wh, p.x, acc[6]); acc[7] = fmaf(wh, p.y, acc[7]);
        }
        // rotate pipeline
        #pragma unroll
        for (int i = 0; i < 4; i++) {
            evA[i] = evB[i]; anA[i] = anB[i]; hvA[i] = hvB[i];
            evB[i] = evC[i]; anB[i] = anC[i]; hvB[i] = hvC[i];
            cC[i] = cD[i];
        }
    }

    const float rden = 1.f / fmaxf(sumw, 1e-10f);
    float a[8];
    #pragma unroll
    for (int j = 0; j < 8; j++) a[j] = acc[j] * rden;

    // layernorm of agg over the head's 32 channels (4 lanes x 8)
    float s0 = 0.f;
    #pragma unroll
    for (int j = 0; j < 8; j++) s0 += a[j];
    float m0 = group4_sum(s0) * (1.f / 32.f);
    float d[8];
    float q0 = 0.f;
    #pragma unroll
    for (int j = 0; j < 8; j++) { d[j] = a[j] - m0; q0 += d[j] * d[j]; }
    float r0 = rsqrtf(group4_sum(q0) * (1.f / 32.f) + 1e-9f);

    float4 sc0a = *(const float4*)(scale + c8);
    float4 sc0b = *(const float4*)(scale + c8 + 4);
    float4 of0a = *(const float4*)(offset + c8);
    float4 of0b = *(const float4*)(offset + c8 + 4);
    const float sc0[8] = {sc0a.x, sc0a.y, sc0a.z, sc0a.w, sc0b.x, sc0b.y, sc0b.z, sc0b.w};
    const float of0[8] = {of0a.x, of0a.y, of0a.z, of0a.w, of0b.x, of0b.y, of0b.z, of0b.w};

    ushort4 nsa = *(const ushort4*)(nsbuf + (size_t)nid * DOUT + c8);
    ushort4 nsb = *(const ushort4*)(nsbuf + (size_t)nid * DOUT + c8 + 4);
    const unsigned short ns[8] = {nsa.x, nsa.y, nsa.z, nsa.w, nsb.x, nsb.y, nsb.z, nsb.w};

    float o[8];
    #pragma unroll
    for (int j = 0; j < 8; j++)
        o[j] = 0.5f * (d[j] * sc0[j] * r0 + of0[j]) + bf2f(ns[j]);

    float4 oa = make_float4(o[0], o[1], o[2], o[3]);
    float4 ob = make_float4(o[4], o[5], o[6], o[7]);
    *(float4*)(out + (size_t)nid * DOUT + c8)     = oa;
    *(float4*)(out + (size_t)nid * DOUT + c8 + 4) = ob;
}

extern "C" void kernel_launch(void* const* d_in, const int* in_sizes, int n_in,
                              void* d_out, int out_size, void* d_ws, size_t ws_size,
                              hipStream_t stream) {
    const float* feat  = (const float*)d_in[0];
    const int*   erow  = (const int*)  d_in[1];
    const int*   ecol  = (const int*)  d_in[2];
    const float* eval  = (const float*)d_in[3];
    const float* W0    = (const float*)d_in[4];
    const float* b0    = (const float*)d_in[5];
    const float* W1    = (const float*)d_in[6];
    const float* b1    = (const float*)d_in[7];
    const float* att   = (const float*)d_in[8];
    const float* scale = (const float*)d_in[9];
    const float* offs  = (const float*)d_in[10];
    const int n = in_sizes[0] / DIN;
    const int E = in_sizes[2];

    unsigned short* featbf  = (unsigned short*)d_ws;                 // n*128
    unsigned short* Wbf     = featbf + (size_t)n * DOUT;             // 256*128
    unsigned short* nsbuf   = Wbf + 2 * DOUT * DIN;                  // n*128
    unsigned short* h_neigh = nsbuf + (size_t)n * DOUT;              // n*128
    float* att_self  = (float*)(h_neigh + (size_t)n * DOUT);
    float* att_neigh = att_self  + (size_t)n * NHEAD;
    int*   rowptr    = (int*)(att_neigh + (size_t)n * NHEAD);

    const int nfeat8 = n * (DIN / 8);
    k0_cvt<<<(nfeat8 + 4096 + 255) / 256, 256, 0, stream>>>(
        feat, W0, W1, (uint4*)featbf, (uint4*)Wbf, nfeat8);
    k1_mfma<<<(n + NPB - 1) / NPB, 512, 0, stream>>>(
        (const uint4*)featbf, (const uint4*)Wbf, b0, b1, att, scale, offs,
        nsbuf, h_neigh, att_self, att_neigh, n);
    k2_rowptr<<<(n + 1 + 255) / 256, 256, 0, stream>>>(erow, rowptr, n, E);
    k3_agg<<<(n + 15) / 16, 256, 0, stream>>>(rowptr, ecol, eval, att_self, att_neigh,
                                              nsbuf, h_neigh, scale, offs,
                                              (float*)d_out, n);
}